// Round 1
// baseline (323.302 us; speedup 1.0000x reference)
//
#include <hip/hip_runtime.h>

// GaussianVoxel: 4 output levels [16,17,zr,64,64] f32, zr in {1,2,4,64}.
// Z_COEFFS = (1,1,1,13): g0..g2 are [1,13,13], g3 is [13,13,13], PATCH=13, PAD=6.
// Output is ~316 MB of zeros plus one small gaussian patch per (b,j) per level.
// Strategy: memset the whole output async (bandwidth-bound floor), then scatter
// the tiny patches with one block per (b,j).

#define B_J 272          // 16*17
#define SIZE2 4096       // 64*64
#define PAD 6
#define PATCH 13
#define PP 169           // 13*13

__global__ __launch_bounds__(256)
void GaussianVoxel_scatter(const float* __restrict__ coords,
                           const float* __restrict__ g0,
                           const float* __restrict__ g1,
                           const float* __restrict__ g2,
                           const float* __restrict__ g3,
                           float* __restrict__ out) {
    const int bj = blockIdx.x;             // 0..271  (b*17 + j)
    // coords layout: [B,J,3] = [bj][x,y,z]
    const int xi = (int)coords[bj * 3 + 0];
    const int yi = (int)coords[bj * 3 + 1];
    const int zi = (int)coords[bj * 3 + 2];

    const int        zrs[4]  = {1, 2, 4, 64};
    const int        zcs[4]  = {1, 1, 1, 13};
    const float*     gs[4]   = {g0, g1, g2, g3};
    // flat offsets of the 4 concatenated outputs
    const long long  offs[4] = {0LL, 1114112LL, 3342336LL, 7798784LL};

    for (int L = 0; L < 4; ++L) {
        const int zr   = zrs[L];
        const int zc   = zcs[L];
        const int zpad = zc >> 1;
        // zidx = ceil(zi*zr/64) - 1, exact integer ceil-div (zi in [0,63])
        const int zidx = (zi * zr + 63) / 64 - 1;

        float* __restrict__ ob = out + offs[L] + (long long)bj * zr * SIZE2;
        const float* __restrict__ g = gs[L];

        const int total = zc * PP;         // 169 or 2197
        for (int t = threadIdx.x; t < total; t += blockDim.x) {
            const int gz  = t / PP;
            const int rem = t - gz * PP;
            const int gy  = rem / PATCH;
            const int gx  = rem - gy * PATCH;
            const int zo  = zidx - zpad + gz;
            const int yo  = yi - PAD + gy;
            const int xo  = xi - PAD + gx;
            if ((unsigned)zo < (unsigned)zr &&
                (unsigned)yo < 64u &&
                (unsigned)xo < 64u) {
                ob[zo * SIZE2 + yo * 64 + xo] = g[t];
            }
        }
    }
}

extern "C" void kernel_launch(void* const* d_in, const int* in_sizes, int n_in,
                              void* d_out, int out_size, void* d_ws, size_t ws_size,
                              hipStream_t stream) {
    const float* coords = (const float*)d_in[0];
    const float* g0     = (const float*)d_in[1];
    const float* g1     = (const float*)d_in[2];
    const float* g2     = (const float*)d_in[3];
    const float* g3     = (const float*)d_in[4];
    float* out = (float*)d_out;

    // Zero the entire output (re-poisoned to 0xAA before every timed call).
    hipMemsetAsync(out, 0, (size_t)out_size * sizeof(float), stream);

    // Scatter the gaussian patches: one block per (b,j).
    GaussianVoxel_scatter<<<B_J, 256, 0, stream>>>(coords, g0, g1, g2, g3, out);
}